// Round 1
// baseline (407.765 us; speedup 1.0000x reference)
//
#include <hip/hip_runtime.h>
#include <hip/hip_bf16.h>

#define TOKENS 4096
#define DDIM 1024
#define HDIM 2048
#define NEXP 8
#define NASSIGN 8192
#define MAX_TILES 80

typedef __attribute__((ext_vector_type(8))) __bf16 bf16x8;
typedef __attribute__((ext_vector_type(4))) float f32x4;
typedef __attribute__((ext_vector_type(4))) unsigned short u16x4;

__device__ __forceinline__ unsigned short f2bf(float f) {
    unsigned int u = __builtin_bit_cast(unsigned int, f);
    u += 0x7fffu + ((u >> 16) & 1u);
    return (unsigned short)(u >> 16);
}

// ---------------- router: logits = x @ Wr + br, top-2 + softmax ----------------
__global__ __launch_bounds__(256) void router_kernel(
    const float* __restrict__ x, const float* __restrict__ Wr, const float* __restrict__ br,
    int* __restrict__ topk_e, float* __restrict__ topk_s)
{
    const int t = blockIdx.x * 4 + (threadIdx.x >> 6);
    const int lane = threadIdx.x & 63;
    const float* xr = x + (long)t * DDIM;
    float acc[8] = {0.f,0.f,0.f,0.f,0.f,0.f,0.f,0.f};
    for (int it = 0; it < DDIM / 64; ++it) {
        const int d = it * 64 + lane;
        const float xv = xr[d];
        const float4 w0 = *(const float4*)(Wr + d * 8);
        const float4 w1 = *(const float4*)(Wr + d * 8 + 4);
        acc[0] += xv * w0.x; acc[1] += xv * w0.y; acc[2] += xv * w0.z; acc[3] += xv * w0.w;
        acc[4] += xv * w1.x; acc[5] += xv * w1.y; acc[6] += xv * w1.z; acc[7] += xv * w1.w;
    }
#pragma unroll
    for (int e = 0; e < 8; ++e) {
        float v = acc[e];
        for (int off = 32; off > 0; off >>= 1) v += __shfl_down(v, off, 64);
        acc[e] = v;
    }
    if (lane == 0) {
        float lg[8];
#pragma unroll
        for (int e = 0; e < 8; ++e) lg[e] = acc[e] + br[e];
        int i0 = 0; float v0 = lg[0];
#pragma unroll
        for (int e = 1; e < 8; ++e) if (lg[e] > v0) { v0 = lg[e]; i0 = e; }
        int i1 = -1; float v1 = -3.4e38f;
#pragma unroll
        for (int e = 0; e < 8; ++e) if (e != i0 && lg[e] > v1) { v1 = lg[e]; i1 = e; }
        const float e1 = expf(v1 - v0);
        const float inv = 1.f / (1.f + e1);
        topk_e[t * 2]     = i0; topk_s[t * 2]     = inv;
        topk_e[t * 2 + 1] = i1; topk_s[t * 2 + 1] = e1 * inv;
    }
}

// ---------------- bucketing: counts -> scan -> scatter + tile map ----------------
__global__ __launch_bounds__(256) void build_lists_kernel(
    const int* __restrict__ topk_e, const float* __restrict__ topk_s,
    int* __restrict__ token_list, float* __restrict__ score_list, int* __restrict__ meta)
{
    __shared__ int cnt[NEXP];
    __shared__ int base[NEXP];
    __shared__ int cur[NEXP];
    const int tid = threadIdx.x;
    if (tid < NEXP) cnt[tid] = 0;
    __syncthreads();
    for (int i = tid; i < NASSIGN; i += 256) atomicAdd(&cnt[topk_e[i]], 1);
    __syncthreads();
    if (tid == 0) {
        int accu = 0;
        for (int e = 0; e < NEXP; ++e) { base[e] = accu; cur[e] = accu; accu += cnt[e]; }
        int ntile = 0;
        for (int e = 0; e < NEXP; ++e) {
            const int c = cnt[e];
            for (int r = 0; r * 128 < c; ++r) {
                meta[1 + ntile] = e;
                meta[1 + MAX_TILES + ntile] = base[e] + r * 128;
                meta[1 + 2 * MAX_TILES + ntile] = (c - r * 128) < 128 ? (c - r * 128) : 128;
                ++ntile;
            }
        }
        meta[0] = ntile;
    }
    __syncthreads();
    for (int i = tid; i < NASSIGN; i += 256) {
        const int e = topk_e[i];
        const int slot = atomicAdd(&cur[e], 1);
        token_list[slot] = i >> 1;
        score_list[slot] = topk_s[i];
    }
}

// ---------------- x fp32 -> bf16 ----------------
__global__ __launch_bounds__(256) void convert_x_kernel(
    const float* __restrict__ src, unsigned short* __restrict__ dst)
{
    const long i = ((long)blockIdx.x * 256 + threadIdx.x) * 4;
    const float4 v = *(const float4*)(src + i);
    u16x4 o;
    o.x = f2bf(v.x); o.y = f2bf(v.y); o.z = f2bf(v.z); o.w = f2bf(v.w);
    *(u16x4*)(dst + i) = o;
}

// ---------------- W [E][K][N] fp32 -> Wt [E][N][K] bf16 (LDS tile transpose) ----------------
__global__ __launch_bounds__(256) void transpose_cvt_kernel(
    const float* __restrict__ src, unsigned short* __restrict__ dst, int K, int N)
{
    __shared__ unsigned short tile[32 * 33];
    const int e = blockIdx.z;
    const int k0 = blockIdx.x * 32;
    const int n0 = blockIdx.y * 32;
    const int r = threadIdx.x >> 3;
    const int c4 = (threadIdx.x & 7) * 4;
    const float4 v = *(const float4*)(src + ((long)e * K + k0 + r) * N + n0 + c4);
    tile[(c4 + 0) * 33 + r] = f2bf(v.x);
    tile[(c4 + 1) * 33 + r] = f2bf(v.y);
    tile[(c4 + 2) * 33 + r] = f2bf(v.z);
    tile[(c4 + 3) * 33 + r] = f2bf(v.w);
    __syncthreads();
    u16x4 o;
    o.x = tile[r * 33 + c4 + 0];
    o.y = tile[r * 33 + c4 + 1];
    o.z = tile[r * 33 + c4 + 2];
    o.w = tile[r * 33 + c4 + 3];
    *(u16x4*)(dst + ((long)e * N + n0 + r) * K + k0 + c4) = o;
}

// ---------------- grouped expert GEMM (m97 structure: 128x128 tile, BK=32) ----------------
// A: [rows][KDIM] bf16 (GEMM1: gathered x rows; GEMM2: contiguous h slots)
// Bt: [E][NDIM][KDIM] bf16 (transposed weights -> k-contiguous)
template<int KDIM, int NDIM, bool G2>
__global__ __launch_bounds__(256, 2) void expert_gemm(
    const unsigned short* __restrict__ Abase,
    const unsigned short* __restrict__ Bt,
    const float* __restrict__ bias,
    unsigned short* __restrict__ Hout,
    float* __restrict__ Out,
    const int* __restrict__ token_list,
    const float* __restrict__ score_list,
    const int* __restrict__ meta)
{
    const int nt = meta[0];
    const int bx = blockIdx.x;
    if (bx >= nt) return;
    const int e = meta[1 + bx];
    const int slot0 = meta[1 + MAX_TILES + bx];
    const int rows_valid = meta[1 + 2 * MAX_TILES + bx];
    const int n0 = blockIdx.y * 128;

    __shared__ unsigned short As[128 * 32];
    __shared__ unsigned short Bs[128 * 32];

    const int tid = threadIdx.x;
    const int lane = tid & 63;
    const int w = tid >> 6;
    const int wm = w & 1;
    const int wn = w >> 1;
    const int quad = lane >> 4;
    const int l15 = lane & 15;

    const unsigned short* aptr[2];
    const unsigned short* bptr[2];
    unsigned short* lA[2];
    unsigned short* lB[2];
#pragma unroll
    for (int c = 0; c < 2; ++c) {
        const int l16 = (c * 4 + w) * 64 + lane;
        const int row = l16 >> 2;
        const int col8 = (l16 & 3) * 8;
        const int rr = row < rows_valid ? row : rows_valid - 1;
        const long arow = G2 ? (long)(slot0 + rr) : (long)token_list[slot0 + rr];
        aptr[c] = Abase + arow * KDIM + col8;
        bptr[c] = Bt + ((long)e * NDIM + n0 + row) * (long)KDIM + col8;
        lA[c] = &As[(c * 4 + w) * 512];
        lB[c] = &Bs[(c * 4 + w) * 512];
    }

    f32x4 acc[4][4] = {};

#pragma unroll 1
    for (int k0 = 0; k0 < KDIM; k0 += 32) {
#pragma unroll
        for (int c = 0; c < 2; ++c) {
            __builtin_amdgcn_global_load_lds(
                (const __attribute__((address_space(1))) unsigned int*)aptr[c],
                (__attribute__((address_space(3))) unsigned int*)lA[c], 16, 0, 0);
            __builtin_amdgcn_global_load_lds(
                (const __attribute__((address_space(1))) unsigned int*)bptr[c],
                (__attribute__((address_space(3))) unsigned int*)lB[c], 16, 0, 0);
            aptr[c] += 32;
            bptr[c] += 32;
        }
        __syncthreads();

        bf16x8 af[4], bfr[4];
#pragma unroll
        for (int mi = 0; mi < 4; ++mi)
            af[mi] = *(const bf16x8*)&As[(wm * 64 + mi * 16 + l15) * 32 + quad * 8];
#pragma unroll
        for (int ni = 0; ni < 4; ++ni)
            bfr[ni] = *(const bf16x8*)&Bs[(wn * 64 + ni * 16 + l15) * 32 + quad * 8];
#pragma unroll
        for (int mi = 0; mi < 4; ++mi)
#pragma unroll
            for (int ni = 0; ni < 4; ++ni)
                acc[mi][ni] = __builtin_amdgcn_mfma_f32_16x16x32_bf16(af[mi], bfr[ni], acc[mi][ni], 0, 0, 0);
        __syncthreads();
    }

#pragma unroll
    for (int mi = 0; mi < 4; ++mi) {
#pragma unroll
        for (int ni = 0; ni < 4; ++ni) {
            const int col = n0 + wn * 64 + ni * 16 + l15;
#pragma unroll
            for (int r = 0; r < 4; ++r) {
                const int row = wm * 64 + mi * 16 + quad * 4 + r;
                if (row < rows_valid) {
                    float v = acc[mi][ni][r] + bias[e * NDIM + col];
                    if (!G2) {
                        v = v > 0.f ? v : 0.f;
                        Hout[(long)(slot0 + row) * NDIM + col] = f2bf(v);
                    } else {
                        const int slot = slot0 + row;
                        const int tok = token_list[slot];
                        const float s = score_list[slot];
                        unsafeAtomicAdd(&Out[(long)tok * NDIM + col], s * v);
                    }
                }
            }
        }
    }
}

extern "C" void kernel_launch(void* const* d_in, const int* in_sizes, int n_in,
                              void* d_out, int out_size, void* d_ws, size_t ws_size,
                              hipStream_t stream)
{
    (void)in_sizes; (void)n_in; (void)out_size; (void)ws_size;
    const float* x  = (const float*)d_in[0];
    const float* Wr = (const float*)d_in[1];
    const float* br = (const float*)d_in[2];
    const float* W1 = (const float*)d_in[3];
    const float* b1 = (const float*)d_in[4];
    const float* W2 = (const float*)d_in[5];
    const float* b2 = (const float*)d_in[6];
    float* out = (float*)d_out;

    char* ws = (char*)d_ws;
    unsigned short* x_bf  = (unsigned short*)(ws);                 // 4096*1024*2   = 8388608
    unsigned short* W1t   = (unsigned short*)(ws + 8388608);       // 8*2048*1024*2 = 33554432
    unsigned short* W2t   = (unsigned short*)(ws + 41943040);      // 33554432
    unsigned short* hbuf  = (unsigned short*)(ws + 75497472);      // 8192*2048*2   = 33554432
    int*   topk_e     = (int*)(ws + 109051904);
    float* topk_s     = (float*)(ws + 109084672);
    int*   token_list = (int*)(ws + 109117440);
    float* score_list = (float*)(ws + 109150208);
    int*   meta       = (int*)(ws + 109182976);

    hipMemsetAsync(d_out, 0, (size_t)TOKENS * DDIM * sizeof(float), stream);

    router_kernel<<<TOKENS / 4, 256, 0, stream>>>(x, Wr, br, topk_e, topk_s);
    convert_x_kernel<<<TOKENS * DDIM / 1024, 256, 0, stream>>>(x, x_bf);
    transpose_cvt_kernel<<<dim3(DDIM / 32, HDIM / 32, NEXP), 256, 0, stream>>>(W1, W1t, DDIM, HDIM);
    transpose_cvt_kernel<<<dim3(HDIM / 32, DDIM / 32, NEXP), 256, 0, stream>>>(W2, W2t, HDIM, DDIM);
    build_lists_kernel<<<1, 256, 0, stream>>>(topk_e, topk_s, token_list, score_list, meta);
    expert_gemm<DDIM, HDIM, false><<<dim3(MAX_TILES, HDIM / 128), 256, 0, stream>>>(
        x_bf, W1t, b1, hbuf, nullptr, token_list, score_list, meta);
    expert_gemm<HDIM, DDIM, true><<<dim3(MAX_TILES, DDIM / 128), 256, 0, stream>>>(
        hbuf, W2t, b2, nullptr, out, token_list, score_list, meta);
}

// Round 3
// 337.482 us; speedup vs baseline: 1.2083x; 1.2083x over previous
//
#include <hip/hip_runtime.h>
#include <hip/hip_bf16.h>

#define TOKENS 4096
#define DDIM 1024
#define HDIM 2048
#define NEXP 8
#define NASSIGN 8192
#define MAX_TILES 80

typedef __attribute__((ext_vector_type(8))) __bf16 bf16x8;
typedef __attribute__((ext_vector_type(4))) float f32x4;
typedef __attribute__((ext_vector_type(4))) unsigned short u16x4;

__device__ __forceinline__ unsigned short f2bf(float f) {
    unsigned int u = __builtin_bit_cast(unsigned int, f);
    u += 0x7fffu + ((u >> 16) & 1u);
    return (unsigned short)(u >> 16);
}

// ---------------- router: logits = x @ Wr + br, top-2 + softmax; also x->bf16 ----------------
__global__ __launch_bounds__(256) void router_kernel(
    const float* __restrict__ x, const float* __restrict__ Wr, const float* __restrict__ br,
    unsigned short* __restrict__ x_bf, int* __restrict__ topk_e, float* __restrict__ topk_s)
{
    const int t = blockIdx.x * 4 + (threadIdx.x >> 6);
    const int lane = threadIdx.x & 63;
    const float* xr = x + (long)t * DDIM;
    unsigned short* xo = x_bf + (long)t * DDIM;
    float acc[8] = {0.f,0.f,0.f,0.f,0.f,0.f,0.f,0.f};
    for (int it = 0; it < DDIM / 64; ++it) {
        const int d = it * 64 + lane;
        const float xv = xr[d];
        xo[d] = f2bf(xv);
        const float4 w0 = *(const float4*)(Wr + d * 8);
        const float4 w1 = *(const float4*)(Wr + d * 8 + 4);
        acc[0] += xv * w0.x; acc[1] += xv * w0.y; acc[2] += xv * w0.z; acc[3] += xv * w0.w;
        acc[4] += xv * w1.x; acc[5] += xv * w1.y; acc[6] += xv * w1.z; acc[7] += xv * w1.w;
    }
#pragma unroll
    for (int e = 0; e < 8; ++e) {
        float v = acc[e];
        for (int off = 32; off > 0; off >>= 1) v += __shfl_down(v, off, 64);
        acc[e] = v;
    }
    if (lane == 0) {
        float lg[8];
#pragma unroll
        for (int e = 0; e < 8; ++e) lg[e] = acc[e] + br[e];
        int i0 = 0; float v0 = lg[0];
#pragma unroll
        for (int e = 1; e < 8; ++e) if (lg[e] > v0) { v0 = lg[e]; i0 = e; }
        int i1 = -1; float v1 = -3.4e38f;
#pragma unroll
        for (int e = 0; e < 8; ++e) if (e != i0 && lg[e] > v1) { v1 = lg[e]; i1 = e; }
        const float e1 = expf(v1 - v0);
        const float inv = 1.f / (1.f + e1);
        topk_e[t * 2]     = i0; topk_s[t * 2]     = inv;
        topk_e[t * 2 + 1] = i1; topk_s[t * 2 + 1] = e1 * inv;
    }
}

// ---------------- bucketing: counts -> scan -> scatter + tile map ----------------
__global__ __launch_bounds__(1024) void build_lists_kernel(
    const int* __restrict__ topk_e, const float* __restrict__ topk_s,
    int* __restrict__ token_list, float* __restrict__ score_list, int* __restrict__ meta)
{
    __shared__ int cnt[NEXP];
    __shared__ int base[NEXP];
    __shared__ int cur[NEXP];
    const int tid = threadIdx.x;
    if (tid < NEXP) cnt[tid] = 0;
    __syncthreads();
    for (int i = tid; i < NASSIGN; i += 1024) atomicAdd(&cnt[topk_e[i]], 1);
    __syncthreads();
    if (tid == 0) {
        int accu = 0;
        for (int e = 0; e < NEXP; ++e) { base[e] = accu; cur[e] = accu; accu += cnt[e]; }
        int ntile = 0;
        for (int e = 0; e < NEXP; ++e) {
            const int c = cnt[e];
            for (int r = 0; r * 128 < c; ++r) {
                meta[1 + ntile] = e;
                meta[1 + MAX_TILES + ntile] = base[e] + r * 128;
                meta[1 + 2 * MAX_TILES + ntile] = (c - r * 128) < 128 ? (c - r * 128) : 128;
                ++ntile;
            }
        }
        meta[0] = ntile;
    }
    __syncthreads();
    for (int i = tid; i < NASSIGN; i += 1024) {
        const int e = topk_e[i];
        const int slot = atomicAdd(&cur[e], 1);
        token_list[slot] = i >> 1;
        score_list[slot] = topk_s[i];
    }
}

// ---------------- W1 [E][D][H] + W2 [E][H][D] fp32 -> [E][N][K] bf16, one launch ----------------
__global__ __launch_bounds__(256) void transpose_cvt_kernel(
    const float* __restrict__ W1, const float* __restrict__ W2,
    unsigned short* __restrict__ W1t, unsigned short* __restrict__ W2t)
{
    __shared__ unsigned short tile[64 * 68];
    const int z = blockIdx.y;           // 0..7 -> W1 experts, 8..15 -> W2 experts
    const bool is1 = z < 8;
    const int e = is1 ? z : z - 8;
    const int K = is1 ? DDIM : HDIM;
    const int N = is1 ? HDIM : DDIM;
    const float* src = (is1 ? W1 : W2) + (long)e * K * N;
    unsigned short* dst = (is1 ? W1t : W2t) + (long)e * K * N;
    const int ktiles = K >> 6;
    const int k0 = (blockIdx.x % ktiles) * 64;
    const int n0 = (blockIdx.x / ktiles) * 64;
    const int r0 = threadIdx.x >> 4;
    const int c4 = (threadIdx.x & 15) * 4;
#pragma unroll
    for (int i = 0; i < 4; ++i) {
        const int r = r0 + i * 16;       // k-row within tile
        const float4 v = *(const float4*)(src + (long)(k0 + r) * N + n0 + c4);
        tile[(c4 + 0) * 68 + r] = f2bf(v.x);
        tile[(c4 + 1) * 68 + r] = f2bf(v.y);
        tile[(c4 + 2) * 68 + r] = f2bf(v.z);
        tile[(c4 + 3) * 68 + r] = f2bf(v.w);
    }
    __syncthreads();
#pragma unroll
    for (int i = 0; i < 4; ++i) {
        const int rn = r0 + i * 16;      // n-row within tile
        u16x4 o;
        o.x = tile[rn * 68 + c4 + 0];
        o.y = tile[rn * 68 + c4 + 1];
        o.z = tile[rn * 68 + c4 + 2];
        o.w = tile[rn * 68 + c4 + 3];
        *(u16x4*)(dst + (long)(n0 + rn) * K + k0 + c4) = o;
    }
}

// ---------------- grouped expert GEMM: 128x128 tile, BK=64, XOR-swizzled LDS ----------------
// A: [rows][KDIM] bf16 (GEMM1: gathered x rows; GEMM2: contiguous h slots)
// Bt: [E][NDIM][KDIM] bf16 (k-contiguous)
template<int KDIM, int NDIM, bool G2>
__global__ __launch_bounds__(256, 2) void expert_gemm(
    const unsigned short* __restrict__ Abase,
    const unsigned short* __restrict__ Bt,
    const float* __restrict__ bias,
    unsigned short* __restrict__ Hout,
    float* __restrict__ Out,
    const int* __restrict__ token_list,
    const float* __restrict__ score_list,
    const int* __restrict__ meta)
{
    const int nt = meta[0];
    // XCD-aware BIJECTIVE partition: XCD ~ bx%8 (gridDim.x=80, multiple of 8).
    // XCD i owns a contiguous, balanced range of q+(i<r) tiles; each tile is
    // covered by exactly one block (the round-2 bug was duplicate tiles ->
    // double atomicAdd in GEMM2).
    const int xcd = blockIdx.x & 7;
    const int off = blockIdx.x >> 3;
    const int q = nt >> 3;
    const int r = nt & 7;
    const int cnt_i = q + (xcd < r ? 1 : 0);
    if (off >= cnt_i) return;
    const int t = xcd * q + (xcd < r ? xcd : r) + off;
    const int e = meta[1 + t];
    const int slot0 = meta[1 + MAX_TILES + t];
    const int rows_valid = meta[1 + 2 * MAX_TILES + t];
    const int n0 = blockIdx.y * 128;

    __shared__ unsigned short As[128 * 64];
    __shared__ unsigned short Bs[128 * 64];

    const int tid = threadIdx.x;
    const int lane = tid & 63;
    const int w = tid >> 6;
    const int wm = w & 1;
    const int wn = w >> 1;
    const int quad = lane >> 4;
    const int l15 = lane & 15;

    // Staging: 1024 16B-chunks per matrix per K-tile; chunk = c*256 + tid.
    // LDS slot for chunk = row*64 + (chunk&7)*8 shorts; the global k-chunk that
    // lands there is (chunk&7) XOR (row&7)  -> bank-conflict-free b128 reads.
    const unsigned short* aptr[4];
    const unsigned short* bptr[4];
    unsigned short* lA[4];
    unsigned short* lB[4];
#pragma unroll
    for (int c = 0; c < 4; ++c) {
        const int chunk = c * 256 + tid;
        const int row = chunk >> 3;
        const int kc = (chunk & 7) ^ (row & 7);
        const int rr = row < rows_valid ? row : rows_valid - 1;
        const long arow = G2 ? (long)(slot0 + rr) : (long)token_list[slot0 + rr];
        aptr[c] = Abase + arow * (long)KDIM + kc * 8;
        bptr[c] = Bt + ((long)e * NDIM + n0 + row) * (long)KDIM + kc * 8;
        lA[c] = &As[(c * 256 + w * 64) * 8];
        lB[c] = &Bs[(c * 256 + w * 64) * 8];
    }

    f32x4 acc[4][4] = {};

#pragma unroll 1
    for (int k0 = 0; k0 < KDIM; k0 += 64) {
#pragma unroll
        for (int c = 0; c < 4; ++c) {
            __builtin_amdgcn_global_load_lds(
                (const __attribute__((address_space(1))) unsigned int*)aptr[c],
                (__attribute__((address_space(3))) unsigned int*)lA[c], 16, 0, 0);
            aptr[c] += 64;
        }
#pragma unroll
        for (int c = 0; c < 4; ++c) {
            __builtin_amdgcn_global_load_lds(
                (const __attribute__((address_space(1))) unsigned int*)bptr[c],
                (__attribute__((address_space(3))) unsigned int*)lB[c], 16, 0, 0);
            bptr[c] += 64;
        }
        __syncthreads();

#pragma unroll
        for (int h = 0; h < 2; ++h) {
            bf16x8 af[4], bfr[4];
#pragma unroll
            for (int mi = 0; mi < 4; ++mi)
                af[mi] = *(const bf16x8*)&As[(wm * 64 + mi * 16 + l15) * 64 + ((h * 4 + quad) ^ (l15 & 7)) * 8];
#pragma unroll
            for (int ni = 0; ni < 4; ++ni)
                bfr[ni] = *(const bf16x8*)&Bs[(wn * 64 + ni * 16 + l15) * 64 + ((h * 4 + quad) ^ (l15 & 7)) * 8];
#pragma unroll
            for (int mi = 0; mi < 4; ++mi)
#pragma unroll
                for (int ni = 0; ni < 4; ++ni)
                    acc[mi][ni] = __builtin_amdgcn_mfma_f32_16x16x32_bf16(af[mi], bfr[ni], acc[mi][ni], 0, 0, 0);
        }
        __syncthreads();
    }

#pragma unroll
    for (int mi = 0; mi < 4; ++mi) {
#pragma unroll
        for (int ni = 0; ni < 4; ++ni) {
            const int col = n0 + wn * 64 + ni * 16 + l15;
#pragma unroll
            for (int rr = 0; rr < 4; ++rr) {
                const int row = wm * 64 + mi * 16 + quad * 4 + rr;
                if (row < rows_valid) {
                    float v = acc[mi][ni][rr] + bias[e * NDIM + col];
                    if (!G2) {
                        v = v > 0.f ? v : 0.f;
                        Hout[(long)(slot0 + row) * NDIM + col] = f2bf(v);
                    } else {
                        const int slot = slot0 + row;
                        const int tok = token_list[slot];
                        const float s = score_list[slot];
                        unsafeAtomicAdd(&Out[(long)tok * NDIM + col], s * v);
                    }
                }
            }
        }
    }
}

extern "C" void kernel_launch(void* const* d_in, const int* in_sizes, int n_in,
                              void* d_out, int out_size, void* d_ws, size_t ws_size,
                              hipStream_t stream)
{
    (void)in_sizes; (void)n_in; (void)out_size; (void)ws_size;
    const float* x  = (const float*)d_in[0];
    const float* Wr = (const float*)d_in[1];
    const float* br = (const float*)d_in[2];
    const float* W1 = (const float*)d_in[3];
    const float* b1 = (const float*)d_in[4];
    const float* W2 = (const float*)d_in[5];
    const float* b2 = (const float*)d_in[6];
    float* out = (float*)d_out;

    char* ws = (char*)d_ws;
    unsigned short* x_bf  = (unsigned short*)(ws);                 // 8388608
    unsigned short* W1t   = (unsigned short*)(ws + 8388608);       // 33554432
    unsigned short* W2t   = (unsigned short*)(ws + 41943040);      // 33554432
    unsigned short* hbuf  = (unsigned short*)(ws + 75497472);      // 33554432
    int*   topk_e     = (int*)(ws + 109051904);
    float* topk_s     = (float*)(ws + 109084672);
    int*   token_list = (int*)(ws + 109117440);
    float* score_list = (float*)(ws + 109150208);
    int*   meta       = (int*)(ws + 109182976);

    hipMemsetAsync(d_out, 0, (size_t)TOKENS * DDIM * sizeof(float), stream);

    router_kernel<<<TOKENS / 4, 256, 0, stream>>>(x, Wr, br, x_bf, topk_e, topk_s);
    build_lists_kernel<<<1, 1024, 0, stream>>>(topk_e, topk_s, token_list, score_list, meta);
    transpose_cvt_kernel<<<dim3(512, 16), 256, 0, stream>>>(W1, W2, W1t, W2t);
    expert_gemm<DDIM, HDIM, false><<<dim3(MAX_TILES, HDIM / 128), 256, 0, stream>>>(
        x_bf, W1t, b1, hbuf, nullptr, token_list, score_list, meta);
    expert_gemm<HDIM, DDIM, true><<<dim3(MAX_TILES, DDIM / 128), 256, 0, stream>>>(
        hbuf, W2t, b2, nullptr, out, token_list, score_list, meta);
}